// Round 1
// baseline (681.162 us; speedup 1.0000x reference)
//
#include <hip/hip_runtime.h>
#include <math.h>

#define N_NODES 50000
#define N_EDGES 800000
#define D 64

// ---------------------------------------------------------------------------
// Kernel 1: scatter-add edge_attr into agg[src], count edges per src node.
// One thread per (edge, feature). Lanes 0..63 of each edge hit 64 consecutive
// floats -> 4 cache lines per edge; atomics resolve in L2.
// ---------------------------------------------------------------------------
__global__ __launch_bounds__(256) void scatter_kernel(
    const float* __restrict__ edge_attr,
    const int* __restrict__ edge_index,   // row 0 = src
    float* __restrict__ agg,              // [N_NODES, D] (pre-zeroed)
    float* __restrict__ counts)           // [N_NODES]     (pre-zeroed)
{
    int gid = blockIdx.x * blockDim.x + threadIdx.x;   // < E*D = 51.2M, fits int
    if (gid >= N_EDGES * D) return;
    int e = gid >> 6;
    int d = gid & 63;
    int src = edge_index[e];
    atomicAdd(&agg[src * D + d], edge_attr[gid]);
    if (d == 0) atomicAdd(&counts[src], 1.0f);
}

// ---------------------------------------------------------------------------
// Kernel 2: node_emb = sigmoid((node_attr + 0.5*agg/max(cnt,1)) @ W^T + b)
// One wave (64 lanes) per node; lane o owns output feature o.
// W stored TRANSPOSED in LDS: lane o reads Wt[i*64+o] -> consecutive lanes,
// conflict-free (2 lanes/bank is free on gfx950). ms[i] broadcast via shfl.
// ---------------------------------------------------------------------------
__global__ __launch_bounds__(256) void node_kernel(
    const float* __restrict__ node_attr,
    const float* __restrict__ agg,
    const float* __restrict__ counts,
    const float* __restrict__ W,          // [D_OUT, D_IN] row-major
    const float* __restrict__ bias,       // [D_OUT]
    float* __restrict__ node_emb)         // [N_NODES, D]
{
    __shared__ float Wt[D * D];           // 16 KiB
    int tid = threadIdx.x;
    for (int k = tid; k < D * D; k += 256) {
        int o = k >> 6, i = k & 63;
        Wt[i * D + o] = W[k];             // transpose into LDS
    }
    __syncthreads();

    int wave = tid >> 6;                  // 0..3
    int o    = tid & 63;
    int n = blockIdx.x * 4 + wave;
    if (n >= N_NODES) return;

    float c = counts[n];
    float scale = 0.5f / fmaxf(c, 1.0f);
    float ms = node_attr[n * D + o] + agg[n * D + o] * scale;  // lane o holds ms[o]

    float acc = bias[o];
    #pragma unroll
    for (int i = 0; i < D; ++i) {
        acc = fmaf(__shfl(ms, i, 64), Wt[i * D + o], acc);
    }
    node_emb[n * D + o] = 1.0f / (1.0f + __expf(-acc));
}

// ---------------------------------------------------------------------------
// Kernel 3: out[e] = 0.5*(node_emb[src[e]] + node_emb[dst[e]])
// float4-vectorized: 16 threads per edge. node_emb (12.8 MB) lives in L2/L3.
// ---------------------------------------------------------------------------
__global__ __launch_bounds__(256) void edge_kernel(
    const int* __restrict__ edge_index,
    const float4* __restrict__ node_emb,  // [N_NODES*16] float4
    float4* __restrict__ out)             // [N_EDGES*16] float4
{
    int t = blockIdx.x * blockDim.x + threadIdx.x;   // < E*16 = 12.8M
    if (t >= N_EDGES * 16) return;
    int e = t >> 4;
    int q = t & 15;
    int src = edge_index[e];
    int dst = edge_index[N_EDGES + e];
    float4 a = node_emb[src * 16 + q];
    float4 c = node_emb[dst * 16 + q];
    float4 r;
    r.x = (a.x + c.x) * 0.5f;
    r.y = (a.y + c.y) * 0.5f;
    r.z = (a.z + c.z) * 0.5f;
    r.w = (a.w + c.w) * 0.5f;
    out[t] = r;
}

extern "C" void kernel_launch(void* const* d_in, const int* in_sizes, int n_in,
                              void* d_out, int out_size, void* d_ws, size_t ws_size,
                              hipStream_t stream) {
    const float* edge_attr  = (const float*)d_in[0];
    const int*   edge_index = (const int*)d_in[1];
    const float* node_attr  = (const float*)d_in[2];
    const float* W          = (const float*)d_in[3];
    const float* bias       = (const float*)d_in[4];
    float* out = (float*)d_out;

    // Workspace layout (floats): agg[N*D] | counts[N] | node_emb[N*D]
    float* agg      = (float*)d_ws;
    float* counts   = agg + (size_t)N_NODES * D;
    float* node_emb = counts + N_NODES;   // byte offset 13,000,000 -> 16B aligned

    // Zero the accumulators (ws is poisoned 0xAA before every timed launch).
    hipMemsetAsync(d_ws, 0, ((size_t)N_NODES * D + N_NODES) * sizeof(float), stream);

    {
        int total = N_EDGES * D;
        scatter_kernel<<<(total + 255) / 256, 256, 0, stream>>>(
            edge_attr, edge_index, agg, counts);
    }
    {
        int blocks = (N_NODES + 3) / 4;
        node_kernel<<<blocks, 256, 0, stream>>>(
            node_attr, agg, counts, W, bias, node_emb);
    }
    {
        int total = N_EDGES * 16;
        edge_kernel<<<(total + 255) / 256, 256, 0, stream>>>(
            edge_index, (const float4*)node_emb, (float4*)out);
    }
}

// Round 2
// 643.129 us; speedup vs baseline: 1.0591x; 1.0591x over previous
//
#include <hip/hip_runtime.h>
#include <math.h>

#define N_NODES 50000
#define N_EDGES 800000
#define D 64
#define NB_SCAN ((N_NODES + 255) / 256)   // 196 blocks of 256

// ---------------------------------------------------------------------------
// Phase 1: histogram of src -> cnt[n]  (int atomics, 800K ops)
// ---------------------------------------------------------------------------
__global__ __launch_bounds__(256) void hist_kernel(
    const int* __restrict__ edge_index, int* __restrict__ cnt)
{
    int e = blockIdx.x * blockDim.x + threadIdx.x;
    if (e >= N_EDGES) return;
    atomicAdd(&cnt[edge_index[e]], 1);
}

// ---------------------------------------------------------------------------
// Phase 2: exclusive scan of cnt -> offs  (3 tiny kernels)
// ---------------------------------------------------------------------------
__global__ __launch_bounds__(256) void scanA_kernel(
    const int* __restrict__ cnt, int* __restrict__ offs, int* __restrict__ bsum)
{
    __shared__ int tmp[256];
    int tid = threadIdx.x;
    int i = blockIdx.x * 256 + tid;
    int v = (i < N_NODES) ? cnt[i] : 0;
    tmp[tid] = v;
    __syncthreads();
    for (int s = 1; s < 256; s <<= 1) {
        int add = (tid >= s) ? tmp[tid - s] : 0;
        __syncthreads();
        tmp[tid] += add;
        __syncthreads();
    }
    if (i < N_NODES) offs[i] = tmp[tid] - v;          // exclusive
    if (tid == 255) bsum[blockIdx.x] = tmp[255];      // block total
}

__global__ __launch_bounds__(256) void scanB_kernel(int* __restrict__ bsum)
{
    __shared__ int tmp[256];
    int tid = threadIdx.x;
    int v = (tid < NB_SCAN) ? bsum[tid] : 0;
    tmp[tid] = v;
    __syncthreads();
    for (int s = 1; s < 256; s <<= 1) {
        int add = (tid >= s) ? tmp[tid - s] : 0;
        __syncthreads();
        tmp[tid] += add;
        __syncthreads();
    }
    bsum[tid] = tmp[tid] - v;                          // exclusive block offsets
}

__global__ __launch_bounds__(256) void scanC_kernel(
    int* __restrict__ offs, const int* __restrict__ bsum, int* __restrict__ cursor)
{
    int i = blockIdx.x * 256 + threadIdx.x;
    if (i >= N_NODES) return;
    int o = offs[i] + bsum[blockIdx.x];
    offs[i] = o;
    cursor[i] = o;
}

// ---------------------------------------------------------------------------
// Phase 3: bucket edge ids by src (counting-sort fill)
// ---------------------------------------------------------------------------
__global__ __launch_bounds__(256) void fill_kernel(
    const int* __restrict__ edge_index, int* __restrict__ cursor,
    int* __restrict__ bucket)
{
    int e = blockIdx.x * blockDim.x + threadIdx.x;
    if (e >= N_EDGES) return;
    int src = edge_index[e];
    int pos = atomicAdd(&cursor[src], 1);
    bucket[pos] = e;
}

// ---------------------------------------------------------------------------
// Phase 4 (fused): per-node gather-mean + linear + sigmoid.
// One wave per node, lane = feature. Edge rows read coalesced (256 B).
// Wt transposed in LDS: lane o reads Wt[i*64+o] (consecutive, conflict-free).
// ---------------------------------------------------------------------------
__global__ __launch_bounds__(256) void node_fused_kernel(
    const float* __restrict__ node_attr,
    const float* __restrict__ edge_attr,
    const int* __restrict__ cnt,
    const int* __restrict__ offs,
    const int* __restrict__ bucket,
    const float* __restrict__ W,
    const float* __restrict__ bias,
    float* __restrict__ node_emb)
{
    __shared__ float Wt[D * D];           // 16 KiB
    int tid = threadIdx.x;
    for (int k = tid; k < D * D; k += 256) {
        int o = k >> 6, i = k & 63;
        Wt[i * D + o] = W[k];
    }
    __syncthreads();

    int n = blockIdx.x * 4 + (tid >> 6);
    int lane = tid & 63;
    if (n >= N_NODES) return;

    int c   = cnt[n];
    int beg = offs[n];

    float sum = 0.0f;
    int k = 0;
    // 2-deep software pipeline on the (uniform) edge-id load
    int e_cur = (c > 0) ? bucket[beg] : 0;
    for (; k < c; ++k) {
        int e_nxt = (k + 1 < c) ? bucket[beg + k + 1] : 0;
        sum += edge_attr[(size_t)e_cur * D + lane];
        e_cur = e_nxt;
    }

    float scale = 0.5f / (float)((c > 0) ? c : 1);
    float ms = node_attr[(size_t)n * D + lane] + sum * scale;

    float acc = bias[lane];
    #pragma unroll
    for (int i = 0; i < D; ++i) {
        acc = fmaf(__shfl(ms, i, 64), Wt[i * D + lane], acc);
    }
    node_emb[(size_t)n * D + lane] = 1.0f / (1.0f + __expf(-acc));
}

// ---------------------------------------------------------------------------
// Phase 5: out[e] = 0.5*(node_emb[src[e]] + node_emb[dst[e]])
// ---------------------------------------------------------------------------
__global__ __launch_bounds__(256) void edge_kernel(
    const int* __restrict__ edge_index,
    const float4* __restrict__ node_emb,  // [N_NODES*16] float4
    float4* __restrict__ out)             // [N_EDGES*16] float4
{
    int t = blockIdx.x * blockDim.x + threadIdx.x;   // < E*16 = 12.8M
    if (t >= N_EDGES * 16) return;
    int e = t >> 4;
    int q = t & 15;
    int src = edge_index[e];
    int dst = edge_index[N_EDGES + e];
    float4 a = node_emb[src * 16 + q];
    float4 c = node_emb[dst * 16 + q];
    float4 r;
    r.x = (a.x + c.x) * 0.5f;
    r.y = (a.y + c.y) * 0.5f;
    r.z = (a.z + c.z) * 0.5f;
    r.w = (a.w + c.w) * 0.5f;
    out[t] = r;
}

extern "C" void kernel_launch(void* const* d_in, const int* in_sizes, int n_in,
                              void* d_out, int out_size, void* d_ws, size_t ws_size,
                              hipStream_t stream) {
    const float* edge_attr  = (const float*)d_in[0];
    const int*   edge_index = (const int*)d_in[1];
    const float* node_attr  = (const float*)d_in[2];
    const float* W          = (const float*)d_in[3];
    const float* bias       = (const float*)d_in[4];
    float* out = (float*)d_out;

    // Workspace layout:
    //   cnt    : int[N_NODES]      @ 0
    //   offs   : int[N_NODES]      @ 200000 B
    //   bsum   : int[256]          @ 400000 B
    //   cursor : int[N_NODES]      @ 401024 B
    //   bucket : int[N_EDGES]      @ 601024 B
    //   node_emb: float[N_NODES*D] @ 3801024 B (16B-aligned)
    char* ws = (char*)d_ws;
    int*   cnt      = (int*)(ws);
    int*   offs     = (int*)(ws + 200000);
    int*   bsum     = (int*)(ws + 400000);
    int*   cursor   = (int*)(ws + 401024);
    int*   bucket   = (int*)(ws + 601024);
    float* node_emb = (float*)(ws + 3801024);

    hipMemsetAsync(cnt, 0, N_NODES * sizeof(int), stream);

    hist_kernel<<<(N_EDGES + 255) / 256, 256, 0, stream>>>(edge_index, cnt);
    scanA_kernel<<<NB_SCAN, 256, 0, stream>>>(cnt, offs, bsum);
    scanB_kernel<<<1, 256, 0, stream>>>(bsum);
    scanC_kernel<<<NB_SCAN, 256, 0, stream>>>(offs, bsum, cursor);
    fill_kernel<<<(N_EDGES + 255) / 256, 256, 0, stream>>>(edge_index, cursor, bucket);
    node_fused_kernel<<<(N_NODES + 3) / 4, 256, 0, stream>>>(
        node_attr, edge_attr, cnt, offs, bucket, W, bias, node_emb);
    edge_kernel<<<(N_EDGES * 16 + 255) / 256, 256, 0, stream>>>(
        edge_index, (const float4*)node_emb, (float4*)out);
}